// Round 6
// baseline (206.288 us; speedup 1.0000x reference)
//
#include <hip/hip_runtime.h>
#include <hip/hip_bf16.h>
#include <cstdint>

// CausalSelfAttention: x[4,2048,1024] @ w_qkv[1024,3072] -> causal attn (H=16, Dh=64) -> @ w_out[1024,1024]
// All heavy compute in bf16 MFMA, fp32 accumulate.
//
// Workspace layout (bytes):
//   xb    @ 0         : 8192*1024 bf16   (16,777,216)
//   wqkvT @ 16777216  : 3072*1024 bf16   ( 6,291,456)   w_qkv transposed to [N][K]; Q cols pre-scaled by 0.125*log2(e)
//   woutT @ 23068672  : 1024*1024 bf16   ( 2,097,152)   w_out  transposed to [N][K]
//   qkvb  @ 25165824  : 8192*3072 bf16   (50,331,648)
//   vtb   @ 75497472  : 4*16*64*2048 bf16(16,777,216)   V transposed to [B,H,Dh,T]
//   ctx   @ 92274688  : 8192*1024 bf16   (16,777,216)

typedef __bf16 bf16x8 __attribute__((ext_vector_type(8)));
typedef __bf16 bf16x4 __attribute__((ext_vector_type(4)));
typedef float  f32x4  __attribute__((ext_vector_type(4)));
typedef float  f32x16 __attribute__((ext_vector_type(16)));
typedef unsigned int u32x4 __attribute__((ext_vector_type(4)));
typedef unsigned int u32x2 __attribute__((ext_vector_type(2)));

#define MFMA16(a, b, c) __builtin_amdgcn_mfma_f32_16x16x32_bf16((a), (b), (c), 0, 0, 0)
#define MFMA32(a, b, c) __builtin_amdgcn_mfma_f32_32x32x16_bf16((a), (b), (c), 0, 0, 0)

// 2^x via v_exp_f32 (HIP has no __exp2f device intrinsic; __builtin_amdgcn_exp2f is the direct map)
__device__ __forceinline__ float fexp2(float x) { return __builtin_amdgcn_exp2f(x); }

__device__ __forceinline__ void gload16(const void* g, void* lds) {
  __builtin_amdgcn_global_load_lds(
      (const __attribute__((address_space(1))) void*)(uintptr_t)g,
      (__attribute__((address_space(3))) void*)(uint32_t)(uintptr_t)lds,
      16, 0, 0);
}

__device__ __forceinline__ uint32_t packbf(float a, float b) {
  uint16_t lo = __builtin_bit_cast(uint16_t, (__bf16)a);
  uint16_t hi = __builtin_bit_cast(uint16_t, (__bf16)b);
  return (uint32_t)lo | ((uint32_t)hi << 16);
}

// cross-half (lane ^ 32) exchange via permlane32_swap (VALU only, no LDS):
__device__ __forceinline__ float halfswap(float x, int hi) {
  uint32_t u = __builtin_bit_cast(uint32_t, x);
  u32x2 rr = __builtin_amdgcn_permlane32_swap(u, u, false, false);
  return __builtin_bit_cast(float, hi ? rr.x : rr.y);
}

// ---------------- fp32 -> bf16 elementwise ----------------
__global__ __launch_bounds__(256) void k_f32_to_bf16(const float* __restrict__ in,
                                                     __bf16* __restrict__ out, int n) {
  int idx = (blockIdx.x * 256 + threadIdx.x) * 4;
  int stride = gridDim.x * 256 * 4;
  for (; idx < n; idx += stride) {
    float4 v = *(const float4*)(in + idx);
    bf16x4 o = { (__bf16)v.x, (__bf16)v.y, (__bf16)v.z, (__bf16)v.w };
    *(bf16x4*)(out + idx) = o;
  }
}

// ---------------- fp32 [R][C] -> bf16 [C][R] transpose; out-rows < nscale get *scale ----------------
__global__ __launch_bounds__(256) void k_transpose_f32_bf16(const float* __restrict__ in,
                                                            __bf16* __restrict__ out,
                                                            int R, int C, float scale, int nscale) {
  __shared__ float t[64][65];
  const int r0 = blockIdx.y * 64, c0 = blockIdx.x * 64;
  const int tx = threadIdx.x & 15, ty = threadIdx.x >> 4;
#pragma unroll
  for (int rr = 0; rr < 4; ++rr) {
    int r = ty + rr * 16;
    float4 v = *(const float4*)(in + (size_t)(r0 + r) * C + c0 + tx * 4);
    t[r][tx * 4 + 0] = v.x; t[r][tx * 4 + 1] = v.y;
    t[r][tx * 4 + 2] = v.z; t[r][tx * 4 + 3] = v.w;
  }
  __syncthreads();
#pragma unroll
  for (int rr = 0; rr < 4; ++rr) {
    int c = ty + rr * 16;
    float sc = (c0 + c < nscale) ? scale : 1.0f;
    bf16x4 o = { (__bf16)(t[tx * 4 + 0][c] * sc), (__bf16)(t[tx * 4 + 1][c] * sc),
                 (__bf16)(t[tx * 4 + 2][c] * sc), (__bf16)(t[tx * 4 + 3][c] * sc) };
    *(bf16x4*)(out + (size_t)(c0 + c) * R + r0 + tx * 4) = o;
  }
}

// ---------------- V slice of qkv -> [B,H,Dh,T] ----------------
__global__ __launch_bounds__(256) void k_vtrans(const __bf16* __restrict__ qkv,
                                                __bf16* __restrict__ vt) {
  __shared__ __bf16 t[64][72];
  const int t0 = blockIdx.x * 64, h = blockIdx.y, b = blockIdx.z;
  const int tx = threadIdx.x & 15, ty = threadIdx.x >> 4;
#pragma unroll
  for (int rr = 0; rr < 4; ++rr) {
    int tt = ty + rr * 16;
    bf16x4 v = *(const bf16x4*)(qkv + (size_t)(b * 2048 + t0 + tt) * 3072 + 2048 + h * 64 + tx * 4);
    t[tt][tx * 4 + 0] = v[0]; t[tt][tx * 4 + 1] = v[1];
    t[tt][tx * 4 + 2] = v[2]; t[tt][tx * 4 + 3] = v[3];
  }
  __syncthreads();
#pragma unroll
  for (int rr = 0; rr < 4; ++rr) {
    int d = ty + rr * 16;
    bf16x4 o = { t[tx * 4 + 0][d], t[tx * 4 + 1][d], t[tx * 4 + 2][d], t[tx * 4 + 3][d] };
    *(bf16x4*)(vt + ((size_t)((b * 16 + h) * 64 + d)) * 2048 + t0 + tx * 4) = o;
  }
}

// ---------------- GEMM 128x128 (m97 structure), used for the out-projection ----------------
template <typename OutT>
__global__ __launch_bounds__(256) void k_gemm_bt(const __bf16* __restrict__ A,
                                                 const __bf16* __restrict__ BT,
                                                 OutT* __restrict__ C,
                                                 int M, int N, int K) {
  __shared__ __align__(16) __bf16 At[128 * 32];
  __shared__ __align__(16) __bf16 Bt[128 * 32];
  const int tid = threadIdx.x;
  const int l = tid & 63, w = tid >> 6;
  const int wr = w >> 1, wc = w & 1;
  const int lr = l & 15, lk = l >> 4;
  const int bm0 = blockIdx.y * 128, bn0 = blockIdx.x * 128;

  const int sm = w * 16 + (l >> 2);
  const int sk = (l & 3) * 8;
  const __bf16* ga0 = A + (size_t)(bm0 + sm) * K + sk;
  const __bf16* ga1 = A + (size_t)(bm0 + 64 + sm) * K + sk;
  const __bf16* gb0 = BT + (size_t)(bn0 + sm) * K + sk;
  const __bf16* gb1 = BT + (size_t)(bn0 + 64 + sm) * K + sk;
  char* lA = (char*)At + w * 1024;
  char* lB = (char*)Bt + w * 1024;

  const f32x4 fz = {0.f, 0.f, 0.f, 0.f};
  f32x4 acc[4][4];
#pragma unroll
  for (int i = 0; i < 4; ++i) {
#pragma unroll
    for (int j = 0; j < 4; ++j) acc[i][j] = fz;
  }

  for (int k0 = 0; k0 < K; k0 += 32) {
    gload16(ga0, lA);
    gload16(ga1, lA + 4096);
    gload16(gb0, lB);
    gload16(gb1, lB + 4096);
    ga0 += 32; ga1 += 32; gb0 += 32; gb1 += 32;
    __syncthreads();
    bf16x8 af[4], bfr[4];
#pragma unroll
    for (int i = 0; i < 4; ++i)
      af[i] = *(const bf16x8*)(At + (wr * 64 + i * 16 + lr) * 32 + lk * 8);
#pragma unroll
    for (int j = 0; j < 4; ++j)
      bfr[j] = *(const bf16x8*)(Bt + (wc * 64 + j * 16 + lr) * 32 + lk * 8);
#pragma unroll
    for (int i = 0; i < 4; ++i) {
#pragma unroll
      for (int j = 0; j < 4; ++j) acc[i][j] = MFMA16(af[i], bfr[j], acc[i][j]);
    }
    __syncthreads();
  }

#pragma unroll
  for (int i = 0; i < 4; ++i) {
#pragma unroll
    for (int j = 0; j < 4; ++j) {
#pragma unroll
      for (int jj = 0; jj < 4; ++jj) {
        int row = bm0 + wr * 64 + i * 16 + lk * 4 + jj;
        int col = bn0 + wc * 64 + j * 16 + lr;
        C[(size_t)row * N + col] = (OutT)acc[i][j][jj];
      }
    }
  }
}

// ---------------- GEMM 256x256, 8-phase counted-vmcnt schedule (T2+T3+T4+T5) ----------------
template <typename OutT>
__global__ __launch_bounds__(512, 2) void k_gemm256(const __bf16* __restrict__ A,
                                                    const __bf16* __restrict__ BT,
                                                    OutT* __restrict__ C,
                                                    int M, int N, int K) {
  __shared__ __align__(16) __bf16 Als[2][2][128 * 64];  // [slot][half][row*64]
  __shared__ __align__(16) __bf16 Bls[2][2][128 * 64];
  const int tid = threadIdx.x;
  const int l = tid & 63, w = tid >> 6;
  const int wm = w >> 2, wn = w & 3;
  const int wnh = wn >> 1, wnl = wn & 1;
  const int lr = l & 15, lk = l >> 4, lr7 = lr & 7;
  const int bm0 = blockIdx.y * 256, bn0 = blockIdx.x * 256;
  const int sr0 = w * 8 + (l >> 3);
  const int sc0 = ((l & 7) ^ (l >> 3)) * 8;
  const int xo0 = (lk ^ lr7) * 8;
  const int xo1 = ((4 + lk) ^ lr7) * 8;

#define STAGE_A(KT, H) do {                                                      \
    const __bf16* s_ = A + (size_t)(bm0 + (H) * 128 + sr0) * K + (KT) * 64 + sc0; \
    char* d_ = (char*)&Als[(KT) & 1][H][0] + w * 1024;                            \
    gload16(s_, d_);                                                              \
    gload16(s_ + (size_t)64 * K, d_ + 8192);                                      \
  } while (0)
#define STAGE_B(KT, H) do {                                                       \
    const __bf16* s_ = BT + (size_t)(bn0 + (H) * 128 + sr0) * K + (KT) * 64 + sc0; \
    char* d_ = (char*)&Bls[(KT) & 1][H][0] + w * 1024;                             \
    gload16(s_, d_);                                                               \
    gload16(s_ + (size_t)64 * K, d_ + 8192);                                       \
  } while (0)
#define LDA(SLOT, QM) do {                                                  \
    _Pragma("unroll") for (int f_ = 0; f_ < 4; ++f_) {                      \
      const __bf16* rp_ = &Als[SLOT][wm][0] + ((QM) * 64 + f_ * 16 + lr) * 64; \
      af[f_][0] = *(const bf16x8*)(rp_ + xo0);                              \
      af[f_][1] = *(const bf16x8*)(rp_ + xo1);                              \
    }                                                                       \
  } while (0)
#define LDB(SLOT, QN) do {                                                  \
    _Pragma("unroll") for (int g_ = 0; g_ < 2; ++g_) {                      \
      const __bf16* rp_ = &Bls[SLOT][wnh][0] + (wnl * 64 + (QN) * 32 + g_ * 16 + lr) * 64; \
      bq[QN][g_][0] = *(const bf16x8*)(rp_ + xo0);                          \
      bq[QN][g_][1] = *(const bf16x8*)(rp_ + xo1);                          \
    }                                                                       \
  } while (0)
#define MFMAQ(QM, QN) do {                                                  \
    __builtin_amdgcn_s_setprio(1);                                          \
    _Pragma("unroll") for (int f_ = 0; f_ < 4; ++f_) {                      \
      _Pragma("unroll") for (int g_ = 0; g_ < 2; ++g_) {                    \
        acc[(QM) * 4 + f_][(QN) * 2 + g_] =                                 \
            MFMA16(af[f_][0], bq[QN][g_][0], acc[(QM) * 4 + f_][(QN) * 2 + g_]); \
        acc[(QM) * 4 + f_][(QN) * 2 + g_] =                                 \
            MFMA16(af[f_][1], bq[QN][g_][1], acc[(QM) * 4 + f_][(QN) * 2 + g_]); \
      }                                                                     \
    }                                                                       \
    __builtin_amdgcn_s_setprio(0);                                          \
  } while (0)
#define BAR() asm volatile("s_barrier" ::: "memory")
#define VMCNT2() asm volatile("s_waitcnt vmcnt(2)" ::: "memory")
#define VMCNT0() asm volatile("s_waitcnt vmcnt(0)" ::: "memory")

  f32x4 acc[8][4];
  const f32x4 fz = {0.f, 0.f, 0.f, 0.f};
#pragma unroll
  for (int m = 0; m < 8; ++m) {
#pragma unroll
    for (int n = 0; n < 4; ++n) acc[m][n] = fz;
  }
  bf16x8 af[4][2], bq[2][2][2];

  STAGE_A(0, 0); STAGE_A(0, 1); STAGE_B(0, 0); STAGE_B(0, 1); STAGE_A(1, 0);
  VMCNT2();
  BAR();

  const int NT = K >> 7;
#pragma unroll 1
  for (int t = 0; t < NT; ++t) {
    const int k1 = 2 * t + 1, k2 = 2 * t + 2, k3 = 2 * t + 3;
    const bool last = (t == NT - 1);
    LDA(0, 0); LDB(0, 0);
    STAGE_A(k1, 1);
    BAR(); MFMAQ(0, 0); BAR();
    LDB(0, 1);
    STAGE_B(k1, 0);
    BAR(); MFMAQ(0, 1); BAR();
    LDA(0, 1);
    STAGE_B(k1, 1);
    BAR(); MFMAQ(1, 1); BAR();
    if (!last) { STAGE_A(k2, 0); VMCNT2(); } else { VMCNT0(); }
    BAR(); MFMAQ(1, 0); BAR();
    LDA(1, 0); LDB(1, 0);
    if (!last) STAGE_A(k2, 1);
    BAR(); MFMAQ(0, 0); BAR();
    LDB(1, 1);
    if (!last) STAGE_B(k2, 0);
    BAR(); MFMAQ(0, 1); BAR();
    LDA(1, 1);
    if (!last) STAGE_B(k2, 1);
    BAR(); MFMAQ(1, 1); BAR();
    if (!last) { STAGE_A(k3, 0); VMCNT2(); }
    BAR(); MFMAQ(1, 0); BAR();
  }

#pragma unroll
  for (int m = 0; m < 8; ++m) {
    const int row = bm0 + wm * 128 + (m >> 2) * 64 + (m & 3) * 16 + lk * 4;
#pragma unroll
    for (int n = 0; n < 4; ++n) {
      const int col = bn0 + wn * 64 + (n >> 1) * 32 + (n & 1) * 16 + lr;
#pragma unroll
      for (int jj = 0; jj < 4; ++jj)
        C[(size_t)(row + jj) * N + col] = (OutT)acc[m][n][jj];
    }
  }
#undef STAGE_A
#undef STAGE_B
#undef LDA
#undef LDB
#undef MFMAQ
#undef BAR
#undef VMCNT2
#undef VMCNT0
}

// ---------------- causal flash attention v4 ----------------
// 1024 blocks (one 128-row q-block each), XCD-chunked grid so each XCD owns 8 (b,h)
// groups exclusively (K/V L2 reuse), longest q-blocks first. 4 blocks/CU resident.
// Swapped QK^T (lane owns one q-row), in-register log2-domain softmax (Q pre-scaled by
// 0.125*log2e), permlane32_swap for all cross-half reductions (no LDS traffic).
__global__ __launch_bounds__(256, 4) void k_attn(const __bf16* __restrict__ qkv,
                                                 const __bf16* __restrict__ vt,
                                                 __bf16* __restrict__ ctx) {
  const int id = blockIdx.x;                    // 0..1023
  const int wg = (id & 7) * 128 + (id >> 3);    // XCD-chunked bijection
  const int qb = 15 - (wg & 15);                // long blocks first within chunk
  const int hb = wg >> 4;                       // 0..63
  const int h = hb & 15, b = hb >> 4;

  const int l = threadIdx.x & 63, w = threadIdx.x >> 6;
  const int q = l & 31, hi = l >> 5, l7 = l & 7;

  __shared__ __align__(16) __bf16 KVs[2][2][64 * 64];  // [buf][K|V^T][...] 32 KB

  const int srow = w * 8 + (l >> 3);
  const int scol = ((l & 7) ^ (l >> 3)) * 8;

  const __bf16* gK = qkv + (size_t)(b * 2048) * 3072 + 1024 + h * 64;  // stride 3072
  const __bf16* gV = vt + (size_t)((b * 16 + h) * 64) * 2048;          // stride 2048

  const float NEG = -1e30f;

  const int q0w = qb * 128 + w * 32;
  const int qg = q0w + q;
  const int nkv = 2 * qb + 2;
  const int kvlast = (q0w + 31) >> 6;

  const __bf16* qp = qkv + (size_t)(b * 2048 + qg) * 3072 + h * 64 + hi * 8;
  bf16x8 qf[4];
#pragma unroll
  for (int d0 = 0; d0 < 4; ++d0) qf[d0] = *(const bf16x8*)(qp + d0 * 16);

  float m_run = NEG, lsum = 0.f;
  f32x16 o0 = (f32x16)(0.0f), o1 = (f32x16)(0.0f);

#pragma unroll
  for (int i = 0; i < 2; ++i) {
    gload16(gK + (size_t)(i * 32 + srow) * 3072 + scol, (char*)&KVs[0][0][0] + i * 4096 + w * 1024);
    gload16(gV + (size_t)(i * 32 + srow) * 2048 + scol, (char*)&KVs[0][1][0] + i * 4096 + w * 1024);
  }
  __syncthreads();

#pragma unroll 1
  for (int kvt = 0; kvt < nkv; ++kvt) {
    const int cur = kvt & 1;
    const int kv0 = kvt * 64;
    if (kvt + 1 < nkv) {
      const int nk0 = kv0 + 64;
#pragma unroll
      for (int i = 0; i < 2; ++i) {
        gload16(gK + (size_t)(nk0 + i * 32 + srow) * 3072 + scol,
                (char*)&KVs[cur ^ 1][0][0] + i * 4096 + w * 1024);
        gload16(gV + (size_t)(i * 32 + srow) * 2048 + nk0 + scol,
                (char*)&KVs[cur ^ 1][1][0] + i * 4096 + w * 1024);
      }
    }
    if (kvt <= kvlast) {
      const __bf16* Kb = &KVs[cur][0][0];
      const __bf16* Vb = &KVs[cur][1][0];

      f32x16 s0 = (f32x16)(0.0f), s1 = (f32x16)(0.0f);
#pragma unroll
      for (int d0 = 0; d0 < 4; ++d0) {
        bf16x8 k0 = *(const bf16x8*)(Kb + (size_t)q * 64 + (((d0 * 2 + hi) ^ l7) * 8));
        bf16x8 k1 = *(const bf16x8*)(Kb + (size_t)(32 + q) * 64 + (((d0 * 2 + hi) ^ l7) * 8));
        s0 = MFMA32(k0, qf[d0], s0);
        s1 = MFMA32(k1, qf[d0], s1);
      }

      if (kvt == kvlast) {
#pragma unroll
        for (int r = 0; r < 16; ++r) {
          const int kl = (r & 3) + 8 * (r >> 2) + 4 * hi;
          if (kv0 + kl > qg) s0[r] = NEG;
          if (kv0 + 32 + kl > qg) s1[r] = NEG;
        }
      }

      // row max: in-lane tree + one permlane half-swap
      float t[8];
#pragma unroll
      for (int i = 0; i < 8; ++i)
        t[i] = fmaxf(fmaxf(s0[i], s0[i + 8]), fmaxf(s1[i], s1[i + 8]));
#pragma unroll
      for (int i = 0; i < 4; ++i) t[i] = fmaxf(t[i], t[i + 4]);
      float mt = fmaxf(fmaxf(t[0], t[1]), fmaxf(t[2], t[3]));
      mt = fmaxf(mt, halfswap(mt, hi));

      // defer-max rescale (log2 domain, THR=8 -> P <= 256)
      if (!__all(mt - m_run <= 8.0f)) {
        const float al = fexp2(m_run - mt);
        lsum *= al;
#pragma unroll
        for (int r = 0; r < 16; ++r) { o0[r] *= al; o1[r] *= al; }
        m_run = mt;
      }

#pragma unroll
      for (int r = 0; r < 16; ++r) {
        s0[r] = fexp2(s0[r] - m_run);
        s1[r] = fexp2(s1[r] - m_run);
      }
      float sa[8];
#pragma unroll
      for (int i = 0; i < 8; ++i) sa[i] = (s0[i] + s0[i + 8]) + (s1[i] + s1[i + 8]);
#pragma unroll
      for (int i = 0; i < 4; ++i) sa[i] += sa[i + 4];
      float sm = (sa[0] + sa[1]) + (sa[2] + sa[3]);
      sm += halfswap(sm, hi);
      lsum += sm;

      // pack P -> bf16 B-fragments via permlane32_swap (T12)
      uint32_t c0[8], c1[8];
#pragma unroll
      for (int j = 0; j < 8; ++j) {
        c0[j] = packbf(s0[2 * j], s0[2 * j + 1]);
        c1[j] = packbf(s1[2 * j], s1[2 * j + 1]);
      }
      u32x4 pk[4];
      {
        u32x2 r0 = __builtin_amdgcn_permlane32_swap(c0[0], c0[2], false, false);
        u32x2 r1 = __builtin_amdgcn_permlane32_swap(c0[1], c0[3], false, false);
        u32x2 r2 = __builtin_amdgcn_permlane32_swap(c0[4], c0[6], false, false);
        u32x2 r3 = __builtin_amdgcn_permlane32_swap(c0[5], c0[7], false, false);
        pk[0].x = r0.x; pk[0].y = r1.x; pk[0].z = r0.y; pk[0].w = r1.y;
        pk[1].x = r2.x; pk[1].y = r3.x; pk[1].z = r2.y; pk[1].w = r3.y;
        u32x2 r4 = __builtin_amdgcn_permlane32_swap(c1[0], c1[2], false, false);
        u32x2 r5 = __builtin_amdgcn_permlane32_swap(c1[1], c1[3], false, false);
        u32x2 r6 = __builtin_amdgcn_permlane32_swap(c1[4], c1[6], false, false);
        u32x2 r7 = __builtin_amdgcn_permlane32_swap(c1[5], c1[7], false, false);
        pk[2].x = r4.x; pk[2].y = r5.x; pk[2].z = r4.y; pk[2].w = r5.y;
        pk[3].x = r6.x; pk[3].y = r7.x; pk[3].z = r6.y; pk[3].w = r7.y;
      }
      bf16x8 pf[4];
#pragma unroll
      for (int kc = 0; kc < 4; ++kc) pf[kc] = __builtin_bit_cast(bf16x8, pk[kc]);

#pragma unroll
      for (int kc = 0; kc < 4; ++kc) {
        bf16x8 vf0 = *(const bf16x8*)(Vb + (size_t)q * 64 + (((kc * 2 + hi) ^ l7) * 8));
        o0 = MFMA32(vf0, pf[kc], o0);
      }
#pragma unroll
      for (int kc = 0; kc < 4; ++kc) {
        bf16x8 vf1 = *(const bf16x8*)(Vb + (size_t)(32 + q) * 64 + (((kc * 2 + hi) ^ l7) * 8));
        o1 = MFMA32(vf1, pf[kc], o1);
      }
    }
    __syncthreads();
  }

  // epilogue: O^T regs -> LDS (stride 72) -> coalesced global
  const float inv = 1.0f / lsum;
  __bf16* Ol = &KVs[0][0][0];
#pragma unroll
  for (int r = 0; r < 16; ++r) {
    const int d = (r & 3) + 8 * (r >> 2) + 4 * hi;
    Ol[(w * 32 + q) * 72 + d]      = (__bf16)(o0[r] * inv);
    Ol[(w * 32 + q) * 72 + 32 + d] = (__bf16)(o1[r] * inv);
  }
  __syncthreads();
  {
    const int row = threadIdx.x >> 1, half = threadIdx.x & 1;
    const __bf16* src = Ol + row * 72 + half * 32;
    __bf16* dst = ctx + (size_t)(b * 2048 + qb * 128 + row) * 1024 + h * 64 + half * 32;
#pragma unroll
    for (int i = 0; i < 4; ++i)
      *(bf16x8*)(dst + i * 8) = *(const bf16x8*)(src + i * 8);
  }
}

extern "C" void kernel_launch(void* const* d_in, const int* in_sizes, int n_in,
                              void* d_out, int out_size, void* d_ws, size_t ws_size,
                              hipStream_t stream) {
  const float* x    = (const float*)d_in[0];   // [8192,1024]
  const float* wqkv = (const float*)d_in[1];   // [1024,3072]
  const float* wout = (const float*)d_in[2];   // [1024,1024]
  float* out = (float*)d_out;                  // [8192,1024]

  char* ws = (char*)d_ws;
  __bf16* xb    = (__bf16*)(ws);
  __bf16* wqkvT = (__bf16*)(ws + 16777216);
  __bf16* woutT = (__bf16*)(ws + 23068672);
  __bf16* qkvb  = (__bf16*)(ws + 25165824);
  __bf16* vtb   = (__bf16*)(ws + 75497472);
  __bf16* ctx   = (__bf16*)(ws + 92274688);

  // Q columns pre-scaled by (1/sqrt(64)) * log2(e) so attention softmax runs in exp2 domain.
  const float qscale = 0.125f * 1.44269504088896340736f;

  k_f32_to_bf16<<<2048, 256, 0, stream>>>(x, xb, 8192 * 1024);
  k_transpose_f32_bf16<<<dim3(48, 16), 256, 0, stream>>>(wqkv, wqkvT, 1024, 3072, qscale, 1024);
  k_transpose_f32_bf16<<<dim3(16, 16), 256, 0, stream>>>(wout, woutT, 1024, 1024, 1.0f, 0);
  k_gemm256<__bf16><<<dim3(12, 32), 512, 0, stream>>>(xb, wqkvT, qkvb, 8192, 3072, 1024);
  k_vtrans<<<dim3(32, 16, 4), 256, 0, stream>>>(qkvb, vtb);
  k_attn<<<1024, 256, 0, stream>>>(qkvb, vtb, ctx);
  k_gemm_bt<float><<<dim3(8, 64), 256, 0, stream>>>(ctx, woutT, out, 8192, 1024, 1024);
}

// Round 7
// 180.020 us; speedup vs baseline: 1.1459x; 1.1459x over previous
//
#include <hip/hip_runtime.h>
#include <hip/hip_bf16.h>
#include <cstdint>

// CausalSelfAttention: x[4,2048,1024] @ w_qkv[1024,3072] -> causal attn (H=16, Dh=64) -> @ w_out[1024,1024]
// All heavy compute in bf16 MFMA, fp32 accumulate.
//
// Workspace layout (bytes):
//   xb    @ 0         : 8192*1024 bf16   (16,777,216)
//   wqkvT @ 16777216  : 3072*1024 bf16   ( 6,291,456)   w_qkv transposed to [N][K]; Q cols pre-scaled by 0.125*log2(e)
//   woutT @ 23068672  : 1024*1024 bf16   ( 2,097,152)   w_out  transposed to [N][K]
//   qkvb  @ 25165824  : 8192*3072 bf16   (50,331,648)
//   vtb   @ 75497472  : 4*16*64*2048 bf16(16,777,216)   V transposed to [B,H,Dh,T]
//   ctx   @ 92274688  : 8192*1024 bf16   (16,777,216)

typedef __bf16 bf16x8 __attribute__((ext_vector_type(8)));
typedef __bf16 bf16x4 __attribute__((ext_vector_type(4)));
typedef float  f32x4  __attribute__((ext_vector_type(4)));
typedef float  f32x16 __attribute__((ext_vector_type(16)));
typedef unsigned int u32x4 __attribute__((ext_vector_type(4)));
typedef unsigned int u32x2 __attribute__((ext_vector_type(2)));

#define MFMA16(a, b, c) __builtin_amdgcn_mfma_f32_16x16x32_bf16((a), (b), (c), 0, 0, 0)
#define MFMA32(a, b, c) __builtin_amdgcn_mfma_f32_32x32x16_bf16((a), (b), (c), 0, 0, 0)

// 2^x via v_exp_f32 (HIP has no __exp2f device intrinsic)
__device__ __forceinline__ float fexp2(float x) { return __builtin_amdgcn_exp2f(x); }

__device__ __forceinline__ void gload16(const void* g, void* lds) {
  __builtin_amdgcn_global_load_lds(
      (const __attribute__((address_space(1))) void*)(uintptr_t)g,
      (__attribute__((address_space(3))) void*)(uint32_t)(uintptr_t)lds,
      16, 0, 0);
}

__device__ __forceinline__ uint32_t packbf(float a, float b) {
  uint16_t lo = __builtin_bit_cast(uint16_t, (__bf16)a);
  uint16_t hi = __builtin_bit_cast(uint16_t, (__bf16)b);
  return (uint32_t)lo | ((uint32_t)hi << 16);
}

// cross-half (lane ^ 32) exchange via permlane32_swap (VALU only, no LDS)
__device__ __forceinline__ float halfswap(float x, int hi) {
  uint32_t u = __builtin_bit_cast(uint32_t, x);
  u32x2 rr = __builtin_amdgcn_permlane32_swap(u, u, false, false);
  return __builtin_bit_cast(float, hi ? rr.x : rr.y);
}

// ---------------- fp32 -> bf16 elementwise ----------------
__global__ __launch_bounds__(256) void k_f32_to_bf16(const float* __restrict__ in,
                                                     __bf16* __restrict__ out, int n) {
  int idx = (blockIdx.x * 256 + threadIdx.x) * 4;
  int stride = gridDim.x * 256 * 4;
  for (; idx < n; idx += stride) {
    float4 v = *(const float4*)(in + idx);
    bf16x4 o = { (__bf16)v.x, (__bf16)v.y, (__bf16)v.z, (__bf16)v.w };
    *(bf16x4*)(out + idx) = o;
  }
}

// ---------------- fp32 [R][C] -> bf16 [C][R] transpose; out-rows < nscale get *scale ----------------
__global__ __launch_bounds__(256) void k_transpose_f32_bf16(const float* __restrict__ in,
                                                            __bf16* __restrict__ out,
                                                            int R, int C, float scale, int nscale) {
  __shared__ float t[64][65];
  const int r0 = blockIdx.y * 64, c0 = blockIdx.x * 64;
  const int tx = threadIdx.x & 15, ty = threadIdx.x >> 4;
#pragma unroll
  for (int rr = 0; rr < 4; ++rr) {
    int r = ty + rr * 16;
    float4 v = *(const float4*)(in + (size_t)(r0 + r) * C + c0 + tx * 4);
    t[r][tx * 4 + 0] = v.x; t[r][tx * 4 + 1] = v.y;
    t[r][tx * 4 + 2] = v.z; t[r][tx * 4 + 3] = v.w;
  }
  __syncthreads();
#pragma unroll
  for (int rr = 0; rr < 4; ++rr) {
    int c = ty + rr * 16;
    float sc = (c0 + c < nscale) ? scale : 1.0f;
    bf16x4 o = { (__bf16)(t[tx * 4 + 0][c] * sc), (__bf16)(t[tx * 4 + 1][c] * sc),
                 (__bf16)(t[tx * 4 + 2][c] * sc), (__bf16)(t[tx * 4 + 3][c] * sc) };
    *(bf16x4*)(out + (size_t)(c0 + c) * R + r0 + tx * 4) = o;
  }
}

// ---------------- V slice of qkv -> [B,H,Dh,T] ----------------
__global__ __launch_bounds__(256) void k_vtrans(const __bf16* __restrict__ qkv,
                                                __bf16* __restrict__ vt) {
  __shared__ __bf16 t[64][72];
  const int t0 = blockIdx.x * 64, h = blockIdx.y, b = blockIdx.z;
  const int tx = threadIdx.x & 15, ty = threadIdx.x >> 4;
#pragma unroll
  for (int rr = 0; rr < 4; ++rr) {
    int tt = ty + rr * 16;
    bf16x4 v = *(const bf16x4*)(qkv + (size_t)(b * 2048 + t0 + tt) * 3072 + 2048 + h * 64 + tx * 4);
    t[tt][tx * 4 + 0] = v[0]; t[tt][tx * 4 + 1] = v[1];
    t[tt][tx * 4 + 2] = v[2]; t[tt][tx * 4 + 3] = v[3];
  }
  __syncthreads();
#pragma unroll
  for (int rr = 0; rr < 4; ++rr) {
    int d = ty + rr * 16;
    bf16x4 o = { t[tx * 4 + 0][d], t[tx * 4 + 1][d], t[tx * 4 + 2][d], t[tx * 4 + 3][d] };
    *(bf16x4*)(vt + ((size_t)((b * 16 + h) * 64 + d)) * 2048 + t0 + tx * 4) = o;
  }
}

// ---------------- GEMM 128x128 (m97 structure), used for the out-projection ----------------
template <typename OutT>
__global__ __launch_bounds__(256) void k_gemm_bt(const __bf16* __restrict__ A,
                                                 const __bf16* __restrict__ BT,
                                                 OutT* __restrict__ C,
                                                 int M, int N, int K) {
  __shared__ __align__(16) __bf16 At[128 * 32];
  __shared__ __align__(16) __bf16 Bt[128 * 32];
  const int tid = threadIdx.x;
  const int l = tid & 63, w = tid >> 6;
  const int wr = w >> 1, wc = w & 1;
  const int lr = l & 15, lk = l >> 4;
  const int bm0 = blockIdx.y * 128, bn0 = blockIdx.x * 128;

  const int sm = w * 16 + (l >> 2);
  const int sk = (l & 3) * 8;
  const __bf16* ga0 = A + (size_t)(bm0 + sm) * K + sk;
  const __bf16* ga1 = A + (size_t)(bm0 + 64 + sm) * K + sk;
  const __bf16* gb0 = BT + (size_t)(bn0 + sm) * K + sk;
  const __bf16* gb1 = BT + (size_t)(bn0 + 64 + sm) * K + sk;
  char* lA = (char*)At + w * 1024;
  char* lB = (char*)Bt + w * 1024;

  const f32x4 fz = {0.f, 0.f, 0.f, 0.f};
  f32x4 acc[4][4];
#pragma unroll
  for (int i = 0; i < 4; ++i) {
#pragma unroll
    for (int j = 0; j < 4; ++j) acc[i][j] = fz;
  }

  for (int k0 = 0; k0 < K; k0 += 32) {
    gload16(ga0, lA);
    gload16(ga1, lA + 4096);
    gload16(gb0, lB);
    gload16(gb1, lB + 4096);
    ga0 += 32; ga1 += 32; gb0 += 32; gb1 += 32;
    __syncthreads();
    bf16x8 af[4], bfr[4];
#pragma unroll
    for (int i = 0; i < 4; ++i)
      af[i] = *(const bf16x8*)(At + (wr * 64 + i * 16 + lr) * 32 + lk * 8);
#pragma unroll
    for (int j = 0; j < 4; ++j)
      bfr[j] = *(const bf16x8*)(Bt + (wc * 64 + j * 16 + lr) * 32 + lk * 8);
#pragma unroll
    for (int i = 0; i < 4; ++i) {
#pragma unroll
      for (int j = 0; j < 4; ++j) acc[i][j] = MFMA16(af[i], bfr[j], acc[i][j]);
    }
    __syncthreads();
  }

#pragma unroll
  for (int i = 0; i < 4; ++i) {
#pragma unroll
    for (int j = 0; j < 4; ++j) {
#pragma unroll
      for (int jj = 0; jj < 4; ++jj) {
        int row = bm0 + wr * 64 + i * 16 + lk * 4 + jj;
        int col = bn0 + wc * 64 + j * 16 + lr;
        C[(size_t)row * N + col] = (OutT)acc[i][j][jj];
      }
    }
  }
}

// ---------------- GEMM 256x256, 8-phase counted-vmcnt schedule (T2+T3+T4+T5) ----------------
template <typename OutT>
__global__ __launch_bounds__(512, 2) void k_gemm256(const __bf16* __restrict__ A,
                                                    const __bf16* __restrict__ BT,
                                                    OutT* __restrict__ C,
                                                    int M, int N, int K) {
  __shared__ __align__(16) __bf16 Als[2][2][128 * 64];  // [slot][half][row*64]
  __shared__ __align__(16) __bf16 Bls[2][2][128 * 64];
  const int tid = threadIdx.x;
  const int l = tid & 63, w = tid >> 6;
  const int wm = w >> 2, wn = w & 3;
  const int wnh = wn >> 1, wnl = wn & 1;
  const int lr = l & 15, lk = l >> 4, lr7 = lr & 7;
  const int bm0 = blockIdx.y * 256, bn0 = blockIdx.x * 256;
  const int sr0 = w * 8 + (l >> 3);
  const int sc0 = ((l & 7) ^ (l >> 3)) * 8;
  const int xo0 = (lk ^ lr7) * 8;
  const int xo1 = ((4 + lk) ^ lr7) * 8;

#define STAGE_A(KT, H) do {                                                      \
    const __bf16* s_ = A + (size_t)(bm0 + (H) * 128 + sr0) * K + (KT) * 64 + sc0; \
    char* d_ = (char*)&Als[(KT) & 1][H][0] + w * 1024;                            \
    gload16(s_, d_);                                                              \
    gload16(s_ + (size_t)64 * K, d_ + 8192);                                      \
  } while (0)
#define STAGE_B(KT, H) do {                                                       \
    const __bf16* s_ = BT + (size_t)(bn0 + (H) * 128 + sr0) * K + (KT) * 64 + sc0; \
    char* d_ = (char*)&Bls[(KT) & 1][H][0] + w * 1024;                             \
    gload16(s_, d_);                                                               \
    gload16(s_ + (size_t)64 * K, d_ + 8192);                                       \
  } while (0)
#define LDA(SLOT, QM) do {                                                  \
    _Pragma("unroll") for (int f_ = 0; f_ < 4; ++f_) {                      \
      const __bf16* rp_ = &Als[SLOT][wm][0] + ((QM) * 64 + f_ * 16 + lr) * 64; \
      af[f_][0] = *(const bf16x8*)(rp_ + xo0);                              \
      af[f_][1] = *(const bf16x8*)(rp_ + xo1);                              \
    }                                                                       \
  } while (0)
#define LDB(SLOT, QN) do {                                                  \
    _Pragma("unroll") for (int g_ = 0; g_ < 2; ++g_) {                      \
      const __bf16* rp_ = &Bls[SLOT][wnh][0] + (wnl * 64 + (QN) * 32 + g_ * 16 + lr) * 64; \
      bq[QN][g_][0] = *(const bf16x8*)(rp_ + xo0);                          \
      bq[QN][g_][1] = *(const bf16x8*)(rp_ + xo1);                          \
    }                                                                       \
  } while (0)
#define MFMAQ(QM, QN) do {                                                  \
    __builtin_amdgcn_s_setprio(1);                                          \
    _Pragma("unroll") for (int f_ = 0; f_ < 4; ++f_) {                      \
      _Pragma("unroll") for (int g_ = 0; g_ < 2; ++g_) {                    \
        acc[(QM) * 4 + f_][(QN) * 2 + g_] =                                 \
            MFMA16(af[f_][0], bq[QN][g_][0], acc[(QM) * 4 + f_][(QN) * 2 + g_]); \
        acc[(QM) * 4 + f_][(QN) * 2 + g_] =                                 \
            MFMA16(af[f_][1], bq[QN][g_][1], acc[(QM) * 4 + f_][(QN) * 2 + g_]); \
      }                                                                     \
    }                                                                       \
    __builtin_amdgcn_s_setprio(0);                                          \
  } while (0)
#define BAR() asm volatile("s_barrier" ::: "memory")
#define VMCNT2() asm volatile("s_waitcnt vmcnt(2)" ::: "memory")
#define VMCNT0() asm volatile("s_waitcnt vmcnt(0)" ::: "memory")

  f32x4 acc[8][4];
  const f32x4 fz = {0.f, 0.f, 0.f, 0.f};
#pragma unroll
  for (int m = 0; m < 8; ++m) {
#pragma unroll
    for (int n = 0; n < 4; ++n) acc[m][n] = fz;
  }
  bf16x8 af[4][2], bq[2][2][2];

  STAGE_A(0, 0); STAGE_A(0, 1); STAGE_B(0, 0); STAGE_B(0, 1); STAGE_A(1, 0);
  VMCNT2();
  BAR();

  const int NT = K >> 7;
#pragma unroll 1
  for (int t = 0; t < NT; ++t) {
    const int k1 = 2 * t + 1, k2 = 2 * t + 2, k3 = 2 * t + 3;
    const bool last = (t == NT - 1);
    LDA(0, 0); LDB(0, 0);
    STAGE_A(k1, 1);
    BAR(); MFMAQ(0, 0); BAR();
    LDB(0, 1);
    STAGE_B(k1, 0);
    BAR(); MFMAQ(0, 1); BAR();
    LDA(0, 1);
    STAGE_B(k1, 1);
    BAR(); MFMAQ(1, 1); BAR();
    if (!last) { STAGE_A(k2, 0); VMCNT2(); } else { VMCNT0(); }
    BAR(); MFMAQ(1, 0); BAR();
    LDA(1, 0); LDB(1, 0);
    if (!last) STAGE_A(k2, 1);
    BAR(); MFMAQ(0, 0); BAR();
    LDB(1, 1);
    if (!last) STAGE_B(k2, 0);
    BAR(); MFMAQ(0, 1); BAR();
    LDA(1, 1);
    if (!last) STAGE_B(k2, 1);
    BAR(); MFMAQ(1, 1); BAR();
    if (!last) { STAGE_A(k3, 0); VMCNT2(); }
    BAR(); MFMAQ(1, 0); BAR();
  }

#pragma unroll
  for (int m = 0; m < 8; ++m) {
    const int row = bm0 + wm * 128 + (m >> 2) * 64 + (m & 3) * 16 + lk * 4;
#pragma unroll
    for (int n = 0; n < 4; ++n) {
      const int col = bn0 + wn * 64 + (n >> 1) * 32 + (n & 1) * 16 + lr;
#pragma unroll
      for (int jj = 0; jj < 4; ++jj)
        C[(size_t)(row + jj) * N + col] = (OutT)acc[m][n][jj];
    }
  }
#undef STAGE_A
#undef STAGE_B
#undef LDA
#undef LDB
#undef MFMAQ
#undef BAR
#undef VMCNT2
#undef VMCNT0
}

// ---------------- causal flash attention v5 ----------------
// Balanced pairing restored: 512 blocks, block pair p handles q-blocks {15-p, p}
// sequentially -> every block does exactly 34 KV iterations. XCD-chunked grid
// (8 bh-groups per XCD for K/V L2 reuse). Triple-buffered K/V staging with counted
// s_waitcnt vmcnt(4): stage(t+1) stays in flight across the barrier (T3/T4), so the
// per-iteration vmcnt(0) drain of the old double-buffer scheme disappears.
// Swapped QK^T, in-register exp2-domain softmax, permlane cross-half reductions.
__global__ __launch_bounds__(256, 2) void k_attn(const __bf16* __restrict__ qkv,
                                                 const __bf16* __restrict__ vt,
                                                 __bf16* __restrict__ ctx) {
  const int id = blockIdx.x;                 // 0..511
  const int wg = (id & 7) * 64 + (id >> 3);  // XCD chunks of 64 blocks
  const int p  = wg & 7;                     // pair index 0..7
  const int hb = wg >> 3;                    // 0..63
  const int h = hb & 15, b = hb >> 4;

  const int l = threadIdx.x & 63, w = threadIdx.x >> 6;
  const int q = l & 31, hi = l >> 5, l7 = l & 7;

  __shared__ __align__(16) __bf16 KVs[3][2][64 * 64];  // [buf][K|V^T] 48 KB triple buffer

  const int srow = w * 8 + (l >> 3);
  const int scol = ((l & 7) ^ (l >> 3)) * 8;

  const __bf16* gK = qkv + (size_t)(b * 2048) * 3072 + 1024 + h * 64;  // stride 3072
  const __bf16* gV = vt + (size_t)((b * 16 + h) * 64) * 2048;          // stride 2048

  const float NEG = -1e30f;

#define STAGE(T, BUF) do {                                                           \
    const int nk0_ = (T) * 64;                                                       \
    _Pragma("unroll") for (int i_ = 0; i_ < 2; ++i_) {                               \
      gload16(gK + (size_t)(nk0_ + i_ * 32 + srow) * 3072 + scol,                    \
              (char*)&KVs[BUF][0][0] + i_ * 4096 + w * 1024);                        \
      gload16(gV + (size_t)(i_ * 32 + srow) * 2048 + nk0_ + scol,                    \
              (char*)&KVs[BUF][1][0] + i_ * 4096 + w * 1024);                        \
    }                                                                                \
  } while (0)

#pragma unroll 1
  for (int ti = 0; ti < 2; ++ti) {
    const int qb = ti ? p : 15 - p;
    const int q0w = qb * 128 + w * 32;
    const int qg = q0w + q;
    const int nkv = 2 * qb + 2;
    const int kvlast = (q0w + 31) >> 6;

    const __bf16* qp = qkv + (size_t)(b * 2048 + qg) * 3072 + h * 64 + hi * 8;
    bf16x8 qf[4];
#pragma unroll
    for (int d0 = 0; d0 < 4; ++d0) qf[d0] = *(const bf16x8*)(qp + d0 * 16);

    float m_run = NEG, lsum = 0.f;
    f32x16 o0 = (f32x16)(0.0f), o1 = (f32x16)(0.0f);

    STAGE(0, 0);  // prologue
    int cur = 0;

#pragma unroll 1
    for (int kvt = 0; kvt < nkv; ++kvt) {
      const int nxt = (cur == 2) ? 0 : cur + 1;
      const int kv0 = kvt * 64;
      if (kvt + 1 < nkv) {
        STAGE(kvt + 1, nxt);
        asm volatile("s_waitcnt vmcnt(4)" ::: "memory");  // stage(kvt) done; (kvt+1) in flight
      } else {
        asm volatile("s_waitcnt vmcnt(0)" ::: "memory");
      }
      asm volatile("s_barrier" ::: "memory");

      if (kvt <= kvlast) {
        const __bf16* Kb = &KVs[cur][0][0];
        const __bf16* Vb = &KVs[cur][1][0];

        f32x16 s0 = (f32x16)(0.0f), s1 = (f32x16)(0.0f);
        __builtin_amdgcn_s_setprio(1);
#pragma unroll
        for (int d0 = 0; d0 < 4; ++d0) {
          bf16x8 k0 = *(const bf16x8*)(Kb + (size_t)q * 64 + (((d0 * 2 + hi) ^ l7) * 8));
          bf16x8 k1 = *(const bf16x8*)(Kb + (size_t)(32 + q) * 64 + (((d0 * 2 + hi) ^ l7) * 8));
          s0 = MFMA32(k0, qf[d0], s0);
          s1 = MFMA32(k1, qf[d0], s1);
        }
        __builtin_amdgcn_s_setprio(0);

        if (kvt == kvlast) {
#pragma unroll
          for (int r = 0; r < 16; ++r) {
            const int kl = (r & 3) + 8 * (r >> 2) + 4 * hi;
            if (kv0 + kl > qg) s0[r] = NEG;
            if (kv0 + 32 + kl > qg) s1[r] = NEG;
          }
        }

        // row max: in-lane tree + one permlane half-swap
        float t[8];
#pragma unroll
        for (int i = 0; i < 8; ++i)
          t[i] = fmaxf(fmaxf(s0[i], s0[i + 8]), fmaxf(s1[i], s1[i + 8]));
#pragma unroll
        for (int i = 0; i < 4; ++i) t[i] = fmaxf(t[i], t[i + 4]);
        float mt = fmaxf(fmaxf(t[0], t[1]), fmaxf(t[2], t[3]));
        mt = fmaxf(mt, halfswap(mt, hi));

        // defer-max rescale (exp2 domain, THR=8)
        if (!__all(mt - m_run <= 8.0f)) {
          const float al = fexp2(m_run - mt);
          lsum *= al;
#pragma unroll
          for (int r = 0; r < 16; ++r) { o0[r] *= al; o1[r] *= al; }
          m_run = mt;
        }

#pragma unroll
        for (int r = 0; r < 16; ++r) {
          s0[r] = fexp2(s0[r] - m_run);
          s1[r] = fexp2(s1[r] - m_run);
        }
        float sa[8];
#pragma unroll
        for (int i = 0; i < 8; ++i) sa[i] = (s0[i] + s0[i + 8]) + (s1[i] + s1[i + 8]);
#pragma unroll
        for (int i = 0; i < 4; ++i) sa[i] += sa[i + 4];
        float sm = (sa[0] + sa[1]) + (sa[2] + sa[3]);
        sm += halfswap(sm, hi);
        lsum += sm;

        // pack P -> bf16 B-fragments via permlane32_swap (T12)
        uint32_t c0[8], c1[8];
#pragma unroll
        for (int j = 0; j < 8; ++j) {
          c0[j] = packbf(s0[2 * j], s0[2 * j + 1]);
          c1[j] = packbf(s1[2 * j], s1[2 * j + 1]);
        }
        u32x4 pk[4];
        {
          u32x2 r0 = __builtin_amdgcn_permlane32_swap(c0[0], c0[2], false, false);
          u32x2 r1 = __builtin_amdgcn_permlane32_swap(c0[1], c0[3], false, false);
          u32x2 r2 = __builtin_amdgcn_permlane32_swap(c0[4], c0[6], false, false);
          u32x2 r3 = __builtin_amdgcn_permlane32_swap(c0[5], c0[7], false, false);
          pk[0].x = r0.x; pk[0].y = r1.x; pk[0].z = r0.y; pk[0].w = r1.y;
          pk[1].x = r2.x; pk[1].y = r3.x; pk[1].z = r2.y; pk[1].w = r3.y;
          u32x2 r4 = __builtin_amdgcn_permlane32_swap(c1[0], c1[2], false, false);
          u32x2 r5 = __builtin_amdgcn_permlane32_swap(c1[1], c1[3], false, false);
          u32x2 r6 = __builtin_amdgcn_permlane32_swap(c1[4], c1[6], false, false);
          u32x2 r7 = __builtin_amdgcn_permlane32_swap(c1[5], c1[7], false, false);
          pk[2].x = r4.x; pk[2].y = r5.x; pk[2].z = r4.y; pk[2].w = r5.y;
          pk[3].x = r6.x; pk[3].y = r7.x; pk[3].z = r6.y; pk[3].w = r7.y;
        }
        bf16x8 pf[4];
#pragma unroll
        for (int kc = 0; kc < 4; ++kc) pf[kc] = __builtin_bit_cast(bf16x8, pk[kc]);

        __builtin_amdgcn_s_setprio(1);
#pragma unroll
        for (int kc = 0; kc < 4; ++kc) {
          bf16x8 vf0 = *(const bf16x8*)(Vb + (size_t)q * 64 + (((kc * 2 + hi) ^ l7) * 8));
          o0 = MFMA32(vf0, pf[kc], o0);
        }
#pragma unroll
        for (int kc = 0; kc < 4; ++kc) {
          bf16x8 vf1 = *(const bf16x8*)(Vb + (size_t)(32 + q) * 64 + (((kc * 2 + hi) ^ l7) * 8));
          o1 = MFMA32(vf1, pf[kc], o1);
        }
        __builtin_amdgcn_s_setprio(0);
      }
      cur = nxt;
    }
    __syncthreads();  // all compute done before LDS reuse as epilogue buffer

    // epilogue: O^T regs -> LDS (stride 72) -> coalesced global
    const float inv = 1.0f / lsum;
    __bf16* Ol = &KVs[0][0][0];
#pragma unroll
    for (int r = 0; r < 16; ++r) {
      const int d = (r & 3) + 8 * (r >> 2) + 4 * hi;
      Ol[(w * 32 + q) * 72 + d]      = (__bf16)(o0[r] * inv);
      Ol[(w * 32 + q) * 72 + 32 + d] = (__bf16)(o1[r] * inv);
    }
    __syncthreads();
    {
      const int row = threadIdx.x >> 1, half = threadIdx.x & 1;
      const __bf16* src = Ol + row * 72 + half * 32;
      __bf16* dst = ctx + (size_t)(b * 2048 + qb * 128 + row) * 1024 + h * 64 + half * 32;
#pragma unroll
      for (int i = 0; i < 4; ++i)
        *(bf16x8*)(dst + i * 8) = *(const bf16x8*)(src + i * 8);
    }
    __syncthreads();  // LDS free before next phase's prologue
  }
#undef STAGE
}

extern "C" void kernel_launch(void* const* d_in, const int* in_sizes, int n_in,
                              void* d_out, int out_size, void* d_ws, size_t ws_size,
                              hipStream_t stream) {
  const float* x    = (const float*)d_in[0];   // [8192,1024]
  const float* wqkv = (const float*)d_in[1];   // [1024,3072]
  const float* wout = (const float*)d_in[2];   // [1024,1024]
  float* out = (float*)d_out;                  // [8192,1024]

  char* ws = (char*)d_ws;
  __bf16* xb    = (__bf16*)(ws);
  __bf16* wqkvT = (__bf16*)(ws + 16777216);
  __bf16* woutT = (__bf16*)(ws + 23068672);
  __bf16* qkvb  = (__bf16*)(ws + 25165824);
  __bf16* vtb   = (__bf16*)(ws + 75497472);
  __bf16* ctx   = (__bf16*)(ws + 92274688);

  // Q columns pre-scaled by (1/sqrt(64)) * log2(e) so attention softmax runs in exp2 domain.
  const float qscale = 0.125f * 1.44269504088896340736f;

  k_f32_to_bf16<<<2048, 256, 0, stream>>>(x, xb, 8192 * 1024);
  k_transpose_f32_bf16<<<dim3(48, 16), 256, 0, stream>>>(wqkv, wqkvT, 1024, 3072, qscale, 1024);
  k_transpose_f32_bf16<<<dim3(16, 16), 256, 0, stream>>>(wout, woutT, 1024, 1024, 1.0f, 0);
  k_gemm256<__bf16><<<dim3(12, 32), 512, 0, stream>>>(xb, wqkvT, qkvb, 8192, 3072, 1024);
  k_vtrans<<<dim3(32, 16, 4), 256, 0, stream>>>(qkvb, vtb);
  k_attn<<<512, 256, 0, stream>>>(qkvb, vtb, ctx);
  k_gemm_bt<float><<<dim3(8, 64), 256, 0, stream>>>(ctx, woutT, out, 8192, 1024, 1024);
}